// Round 16
// baseline (89.307 us; speedup 1.0000x reference)
//
#include <hip/hip_runtime.h>
#include <float.h>

// Tropical (max-plus) linear: y[b,o] = max_i (x[b,i] + W[o,i])
// B=512, I=1024, O=1024, fp32 in/out. No MFMA (max-plus) -> VALU.
//
// Round-16: fp16 PACKED compute via INLINE ASM (v_pk_add_f16 / v_pk_max_f16
// on plain `unsigned` scalars — no ext_vector SSA values, so the r5/r7/r9/r12
// allocator-demotion path cannot trigger; every prior demotion came from
// vector-typed dataflow, never from scalars).
//  * x staged ROW-MAJOR fp16 [b][k]: one u32 = x[k],x[k+1] for a b; op_sel
//    broadcasts lo/hi halves inside pk_add (zero splat cost, k-pair free).
//  * w staged [k][o] fp16: one u32 = an o-pair; acc packed over o.
//  * Per k-pair/thread: 4 ds_read_b128 (was 8) + 128 pk-ops / 128 MACs
//    (1.0 VALU/MAC, was 1.5). Floors: LDS 5.1 + VALU 6.8 = 11.9 us (was 20.4).
//  * r14 barrier-free wave-private double-buffered structure verbatim.
//  * x-frag mapping b = 4*i + tbw -> x reads on distinct bank quads (free).
//  * Accuracy: r12 measured absmax 0.031 << 0.1625 with this exact numeric
//    pipeline (fp16 convert + fp16 add/max). acc init = -inf (0xFC00).

#define B_DIM 512
#define I_DIM 1024
#define O_DIM 1024
#define KT 16            // k per staged chunk

__device__ __forceinline__ void g2lds16(const void* g, void* l) {
    __builtin_amdgcn_global_load_lds(
        (const __attribute__((address_space(1))) void*)g,
        (__attribute__((address_space(3))) void*)l, 16, 0, 0);
}

// packed fp16 ops on plain u32 scalars (VOP3P, single 32-bit VGPR each)
__device__ __forceinline__ unsigned pk_add_bl(unsigned w, unsigned x) {
    unsigned d;   // d.lo = w.lo + x.lo ; d.hi = w.hi + x.lo   (broadcast lo)
    asm("v_pk_add_f16 %0, %1, %2 op_sel:[0,0] op_sel_hi:[1,0]"
        : "=v"(d) : "v"(w), "v"(x));
    return d;
}
__device__ __forceinline__ unsigned pk_add_bh(unsigned w, unsigned x) {
    unsigned d;   // d.lo = w.lo + x.hi ; d.hi = w.hi + x.hi   (broadcast hi)
    asm("v_pk_add_f16 %0, %1, %2 op_sel:[0,1] op_sel_hi:[1,1]"
        : "=v"(d) : "v"(w), "v"(x));
    return d;
}
__device__ __forceinline__ unsigned pk_max(unsigned a, unsigned b) {
    unsigned d;
    asm("v_pk_max_f16 %0, %1, %2" : "=v"(d) : "v"(a), "v"(b));
    return d;
}

// scalar fp16 unpack for the reduce (r13/r15-proven clean)
__device__ __forceinline__ float lo16f(unsigned u) {
    return (float)__builtin_bit_cast(_Float16, (unsigned short)(u & 0xffffu));
}
__device__ __forceinline__ float hi16f(unsigned u) {
    return (float)__builtin_bit_cast(_Float16, (unsigned short)(u >> 16));
}

template <int KB>   // k handled per block
__global__ __launch_bounds__(256, 2) void trop_main(
    const _Float16* __restrict__ xh,   // [B_DIM][I_DIM] row-major fp16
    const _Float16* __restrict__ wh,   // [I_DIM][O_DIM] transposed fp16
    _Float16* __restrict__ part)       // [KSPLIT][B_DIM][O_DIM] fp16 slabs
{
    constexpr int NCH = KB / KT;
    static_assert(KB % KT == 0, "");
    // wave-private double buffers: x [b32][k16] 1 KB, w [k16][o128] 4 KB
    __shared__ __align__(16) char xs[4][2][32 * KT * 2];
    __shared__ __align__(16) char ws[4][2][KT * 128 * 2];

    const int tid  = threadIdx.x;
    const int wave = tid >> 6;          // owns 32 b-rows
    const int lane = tid & 63;
    const int to   = lane & 15;         // o-octet selector (8 contiguous o)
    const int tbw  = lane >> 4;         // b within quad-group: b = 4*i + tbw
    const int o0  = blockIdx.x * 128;
    const int bw0 = blockIdx.y * 128 + 32 * wave;
    const int kz  = blockIdx.z;
    const int kbase = kz * KB;

    // staging lane geometry
    const int xb_l = lane >> 1;         // b-row 0..31 (32 B per row in LDS)
    const int xk_l = (lane & 1) * 16;   // byte offset within row (8 halves)
    const int wk_l = lane >> 4;         // k-subrow 0..3 within one 1KB DMA
    const int wc_l = (lane & 15) * 16;  // byte col within 256B k-row

    unsigned acc_u[8][4];               // packed half2 over o-pairs; SCALARS
    #pragma unroll
    for (int i = 0; i < 8; ++i)
        #pragma unroll
        for (int p = 0; p < 4; ++p)
            acc_u[i][p] = 0xFC00FC00u;  // half2(-inf, -inf)

    auto stage = [&](int c, int buf) {
        const int k0 = kbase + c * KT;
        g2lds16((const char*)xh + ((size_t)(bw0 + xb_l) * I_DIM + k0) * 2 + xk_l,
                &xs[wave][buf][0]);
        #pragma unroll
        for (int t = 0; t < 4; ++t)
            g2lds16((const char*)wh + ((size_t)(k0 + 4 * t + wk_l) * O_DIM + o0) * 2 + wc_l,
                    &ws[wave][buf][t * 1024]);
    };

    auto compute = [&](int buf) {
        const char* xB = &xs[wave][buf][tbw * 32];   // + i*128 (+16 for k8..15)
        const char* wB = &ws[wave][buf][to * 16];    // + k*256
        #pragma unroll
        for (int h = 0; h < 2; ++h) {                // k-halves: k0..7, k8..15
            unsigned xu[8][4];                       // [b-idx][k-pair] scalars
            #pragma unroll
            for (int i = 0; i < 8; ++i) {
                const uint4 v = *(const uint4*)(xB + i * 128 + 16 * h);
                xu[i][0] = v.x; xu[i][1] = v.y; xu[i][2] = v.z; xu[i][3] = v.w;
            }
            #pragma unroll
            for (int q = 0; q < 4; ++q) {            // k-pair within half
                const int k = 8 * h + 2 * q;
                const uint4 w0 = *(const uint4*)(wB + k * 256);
                const uint4 w1 = *(const uint4*)(wB + (k + 1) * 256);
                #pragma unroll
                for (int i = 0; i < 8; ++i) {
                    const unsigned xp = xu[i][q];
                    unsigned s0, s1;
                    s0 = pk_add_bl(w0.x, xp); s1 = pk_add_bh(w1.x, xp);
                    acc_u[i][0] = pk_max(acc_u[i][0], pk_max(s0, s1));
                    s0 = pk_add_bl(w0.y, xp); s1 = pk_add_bh(w1.y, xp);
                    acc_u[i][1] = pk_max(acc_u[i][1], pk_max(s0, s1));
                    s0 = pk_add_bl(w0.z, xp); s1 = pk_add_bh(w1.z, xp);
                    acc_u[i][2] = pk_max(acc_u[i][2], pk_max(s0, s1));
                    s0 = pk_add_bl(w0.w, xp); s1 = pk_add_bh(w1.w, xp);
                    acc_u[i][3] = pk_max(acc_u[i][3], pk_max(s0, s1));
                }
            }
        }
    };

    // barrier-free pipeline (r14): wave-private buffers, compiler vmcnt only
    stage(0, 0);
    #pragma unroll
    for (int c = 0; c < NCH; ++c) {
        if (c + 1 < NCH) stage(c + 1, (c + 1) & 1);
        compute(c & 1);
    }

    // epilogue: uint4 stores of packed fp16 (8 consecutive o per thread)
    _Float16* pout = part + (size_t)kz * (B_DIM * O_DIM);
    #pragma unroll
    for (int i = 0; i < 8; ++i) {
        const int b = bw0 + 4 * i + tbw;
        const uint4 v = make_uint4(acc_u[i][0], acc_u[i][1],
                                   acc_u[i][2], acc_u[i][3]);
        *(uint4*)((char*)pout + ((size_t)b * O_DIM + o0 + 8 * to) * 2) = v;
    }
}

// ---- prep: z=0 convert x->xh row-major; z=1,2 transpose+convert W->wh
__global__ __launch_bounds__(256) void prep_xw(
    const float* __restrict__ x, _Float16* __restrict__ xh,
    const float* __restrict__ W, _Float16* __restrict__ wh)
{
    const int tx = threadIdx.x;   // 0..31
    const int ty = threadIdx.y;   // 0..7
    const int z  = blockIdx.z;
    const int r0 = blockIdx.y * 32;
    const int c0 = blockIdx.x * 32;
    if (z == 0) {                 // plain convert, coalesced
        #pragma unroll
        for (int i = 0; i < 4; ++i) {
            const size_t idx = (size_t)(r0 + ty + 8 * i) * I_DIM + c0 + tx;
            xh[idx] = (_Float16)x[idx];
        }
        return;
    }
    __shared__ float tile[32][33];
    const float* in = W + (size_t)(z - 1) * 512 * I_DIM;
    _Float16* out = wh + (z - 1) * 512;
    #pragma unroll
    for (int i = 0; i < 4; ++i)
        tile[ty + 8 * i][tx] = in[(size_t)(r0 + ty + 8 * i) * I_DIM + c0 + tx];
    __syncthreads();
    #pragma unroll
    for (int i = 0; i < 4; ++i)
        out[(size_t)(c0 + ty + 8 * i) * O_DIM + r0 + tx] =
            (_Float16)tile[tx][ty + 8 * i];
}

// ---- reduce fp16 slabs -> fp32 y (r15-verified)
template <int KS>
__global__ __launch_bounds__(256) void trop_reduce_h(
    const _Float16* __restrict__ part, float* __restrict__ y)
{
    constexpr size_t N = (size_t)B_DIM * O_DIM;
    const int idx = blockIdx.x * 256 + threadIdx.x;
    float m0 = -FLT_MAX, m1 = -FLT_MAX, m2 = -FLT_MAX, m3 = -FLT_MAX;
    float m4 = -FLT_MAX, m5 = -FLT_MAX, m6 = -FLT_MAX, m7 = -FLT_MAX;
    #pragma unroll
    for (int s = 0; s < KS; ++s) {
        const uint4 v = *(const uint4*)((const char*)part + (s * N + (size_t)idx * 8) * 2);
        m0 = fmaxf(m0, lo16f(v.x)); m1 = fmaxf(m1, hi16f(v.x));
        m2 = fmaxf(m2, lo16f(v.y)); m3 = fmaxf(m3, hi16f(v.y));
        m4 = fmaxf(m4, lo16f(v.z)); m5 = fmaxf(m5, hi16f(v.z));
        m6 = fmaxf(m6, lo16f(v.w)); m7 = fmaxf(m7, hi16f(v.w));
    }
    const float4 o0 = make_float4(m0, m1, m2, m3);
    const float4 o1 = make_float4(m4, m5, m6, m7);
    ((float4*)y)[2 * idx]     = o0;
    ((float4*)y)[2 * idx + 1] = o1;
}

// correctness-net fallback if d_ws is tiny (fp32, exact)
__global__ __launch_bounds__(256) void trop_naive(
    const float* __restrict__ x, const float* __restrict__ W,
    float* __restrict__ y)
{
    const int idx = blockIdx.x * 256 + threadIdx.x;
    const int b = idx / O_DIM, o = idx % O_DIM;
    float m = -FLT_MAX;
    for (int i = 0; i < I_DIM; ++i)
        m = fmaxf(m, x[b * I_DIM + i] + W[o * I_DIM + i]);
    y[idx] = m;
}

extern "C" void kernel_launch(void* const* d_in, const int* in_sizes, int n_in,
                              void* d_out, int out_size, void* d_ws, size_t ws_size,
                              hipStream_t stream) {
    const float* x = (const float*)d_in[0];
    const float* W = (const float*)d_in[1];
    float* y = (float*)d_out;

    const size_t slab_h = (size_t)B_DIM * O_DIM * 2;   // 1 MB fp16
    const size_t xh_sz  = (size_t)B_DIM * I_DIM * 2;   // 1 MB
    const size_t wh_sz  = (size_t)O_DIM * I_DIM * 2;   // 2 MB
    const dim3 rgrid(B_DIM * O_DIM / 8 / 256);
    const dim3 tgrid(I_DIM / 32, 512 / 32, 3);
    const dim3 tblk(32, 8);

    if (ws_size >= 16 * slab_h + xh_sz + wh_sz) {        // 19 MB
        _Float16* part = (_Float16*)d_ws;
        _Float16* xh = (_Float16*)((char*)d_ws + 16 * slab_h);
        _Float16* wh = xh + (size_t)B_DIM * I_DIM;
        prep_xw<<<tgrid, tblk, 0, stream>>>(x, xh, W, wh);
        trop_main<I_DIM / 16><<<dim3(8, 4, 16), 256, 0, stream>>>(xh, wh, part);
        trop_reduce_h<16><<<rgrid, 256, 0, stream>>>(part, y);
    } else if (ws_size >= 8 * slab_h + xh_sz + wh_sz) {  // 11 MB
        _Float16* part = (_Float16*)d_ws;
        _Float16* xh = (_Float16*)((char*)d_ws + 8 * slab_h);
        _Float16* wh = xh + (size_t)B_DIM * I_DIM;
        prep_xw<<<tgrid, tblk, 0, stream>>>(x, xh, W, wh);
        trop_main<I_DIM / 8><<<dim3(8, 4, 8), 256, 0, stream>>>(xh, wh, part);
        trop_reduce_h<8><<<rgrid, 256, 0, stream>>>(part, y);
    } else if (ws_size >= slab_h + xh_sz + wh_sz) {      // 4 MB: no K-split
        _Float16* part = (_Float16*)d_ws;
        _Float16* xh = (_Float16*)((char*)d_ws + slab_h);
        _Float16* wh = xh + (size_t)B_DIM * I_DIM;
        prep_xw<<<tgrid, tblk, 0, stream>>>(x, xh, W, wh);
        trop_main<I_DIM><<<dim3(8, 4, 1), 256, 0, stream>>>(xh, wh, part);
        trop_reduce_h<1><<<rgrid, 256, 0, stream>>>(part, y);
    } else {
        trop_naive<<<dim3(B_DIM * O_DIM / 256), 256, 0, stream>>>(x, W, y);
    }
}